// Round 17
// baseline (137.724 us; speedup 1.0000x reference)
//
#include <hip/hip_runtime.h>
#include <stdint.h>

typedef unsigned short u16;
typedef __attribute__((ext_vector_type(8))) short bf16x8;
typedef __attribute__((ext_vector_type(4))) float f32x4;
typedef __attribute__((ext_vector_type(4))) unsigned short u16x4;

__device__ __forceinline__ u16 f2bf(float f) {
  union { float f; uint32_t u; } c; c.f = f;
  uint32_t u = c.u;
  return (u16)((u + 0x7fffu + ((u >> 16) & 1u)) >> 16);
}

__device__ __forceinline__ uint32_t pk_bf16(float lo, float hi) {
  uint32_t d;
  asm("v_cvt_pk_bf16_f32 %0, %1, %2" : "=v"(d) : "v"(lo), "v"(hi));
  return d;
}

__device__ __forceinline__ void gload_lds16(const u16* g, u16* l) {
  __builtin_amdgcn_global_load_lds(
      (const __attribute__((address_space(1))) void*)g,
      (__attribute__((address_space(3))) void*)l, 16, 0, 0);
}

// one launch: x -> xb, Wq|Wk|Wv -> Wcat, Wo -> Wob
__global__ void cast_all(const float* __restrict__ x,
                         const float* __restrict__ Wq, const float* __restrict__ Wk,
                         const float* __restrict__ Wv, const float* __restrict__ Wo,
                         u16* __restrict__ xb, u16* __restrict__ Wcat, u16* __restrict__ Wob) {
  int i = (blockIdx.x * blockDim.x + threadIdx.x) * 4;
  const int stride = gridDim.x * blockDim.x * 4;
  for (; i < 8388608; i += stride) {
    const float* src;
    u16* dst;
    if (i < 4194304) {
      src = x + i; dst = xb + i;
    } else {
      const int j = i - 4194304;
      const int sel = j >> 20, off = j & 1048575;
      src = ((sel == 0) ? Wq : (sel == 1) ? Wk : (sel == 2) ? Wv : Wo) + off;
      dst = (sel < 3) ? (Wcat + j) : (Wob + off);
    }
    float4 v = *reinterpret_cast<const float4*>(src);
    u16x4 o = { f2bf(v.x), f2bf(v.y), f2bf(v.z), f2bf(v.w) };
    *reinterpret_cast<u16x4*>(dst) = o;
  }
}

#define QSCALE 0.18033688011112042f  /* 1/sqrt(64) * log2(e) */

// C = A @ B^T.  128x128 tile, BK=32, LDS double-buffer with counted vmcnt.
// EPI 0: scatter Q(pre-scaled)/K/Vt.  V-blocks (n0>=2048, block-uniform)
// compute the TRANSPOSED product via operand-swapped MFMA (B@A^T), so the
// Vt store has s = ...+lr contiguous per lane (32B-coalesced) instead of
// 2B scatter at 4KB stride.  Values bit-identical (same dot products).
// EPI 1: fp32 out + bias.
template<int EPI>
__global__ __launch_bounds__(256) void gemm_bt(
    const u16* __restrict__ A, const u16* __restrict__ B,
    int M, int N, int K,
    u16* __restrict__ o0, u16* __restrict__ o1, u16* __restrict__ o2,
    float* __restrict__ fo, const float* __restrict__ bias)
{
  __shared__ __align__(16) u16 As[2][128 * 32];
  __shared__ __align__(16) u16 Bs[2][128 * 32];
  const int tid = threadIdx.x;
  const int w = tid >> 6, l = tid & 63;
  const int m0 = blockIdx.y * 128, n0 = blockIdx.x * 128;
  const int arow = (w << 4) + (l >> 2);
  const int acol = (l & 3) << 3;
  const int wr = (w >> 1) << 6, wc = (w & 1) << 6;
  const int lr = l & 15, hi = l >> 4;
  const int lk = hi << 3;
  const int matb = n0 >> 10;               // block-uniform output selector
  const bool vswap = (EPI == 0) && (matb == 2);
  f32x4 acc[4][4] = {};

  const u16* Ap = A + (size_t)(m0 + arow) * K + acol;
  const u16* Bp = B + (size_t)(n0 + arow) * K + acol;
  const int so = (w << 9);

  gload_lds16(Ap, &As[0][so]);
  gload_lds16(Ap + (size_t)64 * K, &As[0][so + 2048]);
  gload_lds16(Bp, &Bs[0][so]);
  gload_lds16(Bp + (size_t)64 * K, &Bs[0][so + 2048]);

  int buf = 0;
  for (int k0 = 0; k0 < K; k0 += 32) {
    if (k0 + 32 < K) {
      const int nb = buf ^ 1;
      gload_lds16(Ap + k0 + 32, &As[nb][so]);
      gload_lds16(Ap + (size_t)64 * K + k0 + 32, &As[nb][so + 2048]);
      gload_lds16(Bp + k0 + 32, &Bs[nb][so]);
      gload_lds16(Bp + (size_t)64 * K + k0 + 32, &Bs[nb][so + 2048]);
      asm volatile("s_waitcnt vmcnt(4)" ::: "memory");
    } else {
      asm volatile("s_waitcnt vmcnt(0)" ::: "memory");
    }
    __builtin_amdgcn_sched_barrier(0);
    __builtin_amdgcn_s_barrier();
    bf16x8 af[4], bfr[4];
#pragma unroll
    for (int m = 0; m < 4; ++m)
      af[m] = *(const bf16x8*)(&As[buf][0] + (wr + m * 16 + lr) * 32 + lk);
#pragma unroll
    for (int n = 0; n < 4; ++n)
      bfr[n] = *(const bf16x8*)(&Bs[buf][0] + (wc + n * 16 + lr) * 32 + lk);
    __builtin_amdgcn_s_setprio(1);
    if (vswap) {
#pragma unroll
      for (int m = 0; m < 4; ++m)
#pragma unroll
        for (int n = 0; n < 4; ++n)
          acc[m][n] = __builtin_amdgcn_mfma_f32_16x16x32_bf16(bfr[n], af[m], acc[m][n], 0, 0, 0);
    } else {
#pragma unroll
      for (int m = 0; m < 4; ++m)
#pragma unroll
        for (int n = 0; n < 4; ++n)
          acc[m][n] = __builtin_amdgcn_mfma_f32_16x16x32_bf16(af[m], bfr[n], acc[m][n], 0, 0, 0);
    }
    __builtin_amdgcn_s_setprio(0);
    __builtin_amdgcn_s_barrier();
    buf ^= 1;
  }

  if (vswap) {
    // acc[mm][nn] = (B@A^T) sub-tile: row = n_local (dh), col = m_local (s)
    const int b = m0 >> 11, s0 = m0 & 2047;
    const int nc0 = n0 - 2048;
#pragma unroll
    for (int mm = 0; mm < 4; ++mm) {
#pragma unroll
      for (int nn = 0; nn < 4; ++nn) {
        const int ml = wr + mm * 16 + lr;         // s offset (contiguous per lane)
        const int nlb = wc + nn * 16 + (hi << 2); // dh row base (+r)
#pragma unroll
        for (int r = 0; r < 4; ++r) {
          const int col = nc0 + nlb + r;
          const int h = col >> 6, dh = col & 63;
          o2[(((size_t)(b * 16 + h)) * 64 + dh) * 2048 + s0 + ml] = f2bf(acc[mm][nn][r]);
        }
      }
    }
    return;
  }

#pragma unroll
  for (int mm = 0; mm < 4; ++mm) {
#pragma unroll
    for (int nn = 0; nn < 4; ++nn) {
      const int ng = n0 + wc + nn * 16 + lr;
      if (EPI == 0) {
        const int col = ng & 1023;
        const int h = col >> 6, dh = col & 63;
#pragma unroll
        for (int r = 0; r < 4; ++r) {
          const int mg = m0 + wr + mm * 16 + (hi << 2) + r;
          const int b = mg >> 11, s = mg & 2047;
          if (matb == 0)
            o0[(((size_t)(b * 16 + h)) * 2048 + s) * 64 + dh] = f2bf(acc[mm][nn][r] * QSCALE);
          else
            o1[(((size_t)(b * 16 + h)) * 2048 + s) * 64 + dh] = f2bf(acc[mm][nn][r]);
        }
      } else {
        const float bv = bias[ng];
#pragma unroll
        for (int r = 0; r < 4; ++r) {
          const int mg = m0 + wr + mm * 16 + (hi << 2) + r;
          fo[(size_t)mg * N + ng] = acc[mm][nn][r] + bv;
        }
      }
    }
  }
}

// Flash attention, causal.  UNIFORM-WORK pairing: grid (16,32); block p
// processes q-tile p (p+1 kv-phases) then q-tile 31-p (32-p phases) with
// the same 4 waves -> every block runs exactly 33 phases.  Inner pipeline:
// K/V reg-staged (global->reg, ds_write to buf^1 at phase end), ONE
// barrier per phase, loads issued 2 tiles ahead; swapped QK^T -> in-lane
// exp2 softmax; per-wave PT bounce.
__global__ __launch_bounds__(256) void flash_attn(
    const u16* __restrict__ Qg, const u16* __restrict__ Kg,
    const u16* __restrict__ Vtg, u16* __restrict__ ctx)
{
  __shared__ __align__(16) u16 Ks[2][4096];
  __shared__ __align__(16) u16 Vts[2][4096];
  __shared__ __align__(16) u16 PT[4][1024];
  const int tid = threadIdx.x, w = tid >> 6, l = tid & 63;
  const int lr = l & 15, hi = l >> 4;
  const int p = blockIdx.x;          // pair index [0,16)
  const int bh = blockIdx.y;
  const size_t kqbase = (size_t)bh * (2048 * 64);
  const int h = bh & 15, b = bh >> 4;

  const int c0 = w * 128 + l;
  const int c1 = c0 + 64;
  const int r0 = c0 >> 3, p0 = c0 & 7;
  const int r1 = c1 >> 3, p1 = c1 & 7;
  const u16* kg0 = Kg + kqbase + r0 * 64 + p0 * 8;
  const u16* kg1 = Kg + kqbase + r1 * 64 + p1 * 8;
  const u16* vg0 = Vtg + kqbase + (size_t)r0 * 2048 + p0 * 8;
  const u16* vg1 = Vtg + kqbase + (size_t)r1 * 2048 + p1 * 8;
  const int kw0 = (r0 << 7) + ((p0 ^ (r0 & 7)) << 4);
  const int kw1 = (r1 << 7) + ((p1 ^ (r1 & 7)) << 4);

  for (int seg = 0; seg < 2; ++seg) {
    const int qt = seg ? (31 - p) : p;
    const int q0 = qt * 64;
    const int nkt = qt + 1;
    const int qg = q0 + w * 16 + lr;

    if (seg) __builtin_amdgcn_s_barrier();   // protect LDS reuse across segments

    bf16x8 qf[2];
    {
      const u16* qp = Qg + kqbase + (size_t)(q0 + w * 16 + lr) * 64 + hi * 8;
      qf[0] = *(const bf16x8*)(qp);
      qf[1] = *(const bf16x8*)(qp + 32);
    }

    f32x4 acc[4] = {};
    float lsum = 0.0f;

    // prologue: tile 0 -> regs -> buf0; issue tile 1 loads
    bf16x8 sk0 = *(const bf16x8*)kg0;
    bf16x8 sk1 = *(const bf16x8*)kg1;
    bf16x8 sv0 = *(const bf16x8*)vg0;
    bf16x8 sv1 = *(const bf16x8*)vg1;
    *(bf16x8*)((char*)&Ks[0][0] + kw0) = sk0;
    *(bf16x8*)((char*)&Ks[0][0] + kw1) = sk1;
    *(bf16x8*)((char*)&Vts[0][0] + kw0) = sv0;
    *(bf16x8*)((char*)&Vts[0][0] + kw1) = sv1;
    if (nkt > 1) {
      sk0 = *(const bf16x8*)(kg0 + 4096);
      sk1 = *(const bf16x8*)(kg1 + 4096);
      sv0 = *(const bf16x8*)(vg0 + 64);
      sv1 = *(const bf16x8*)(vg1 + 64);
    }
    asm volatile("s_waitcnt lgkmcnt(0)" ::: "memory");
    __builtin_amdgcn_sched_barrier(0);
    __builtin_amdgcn_s_barrier();

    int buf = 0;
    for (int kt = 0; kt < nkt; ++kt) {
      {
        const u16* ksb = &Ks[buf][0];
        const u16* vsb = &Vts[buf][0];
        f32x4 sv[4];
        __builtin_amdgcn_s_setprio(1);
#pragma unroll
        for (int cf = 0; cf < 4; ++cf) {
          f32x4 z = {};
#pragma unroll
          for (int ch = 0; ch < 2; ++ch) {
            const int krow = cf * 16 + lr;
            const int boff = ((krow << 7) + ((ch * 32 + hi * 8) << 1)) ^ ((krow & 7) << 4);
            bf16x8 kf = *(const bf16x8*)((const char*)ksb + boff);
            z = __builtin_amdgcn_mfma_f32_16x16x32_bf16(kf, qf[ch], z, 0, 0, 0);
          }
          sv[cf] = z;
        }
        __builtin_amdgcn_s_setprio(0);

        const bool diag = (kt == nkt - 1);
        const int kb = kt * 64 + hi * 4;
        float ts = 0.0f;
#pragma unroll
        for (int cf = 0; cf < 4; ++cf) {
          f32x4 pv;
#pragma unroll
          for (int r = 0; r < 4; ++r) {
            float s = sv[cf][r];
            if (diag && (kb + cf * 16 + r) > qg) s = -1e30f;
            pv[r] = exp2f(s);
          }
          sv[cf] = pv;
          ts += (pv[0] + pv[1]) + (pv[2] + pv[3]);
        }
        lsum += ts;

        {
          const int rowb = lr << 7;
          const int swz = (lr & 7) << 4;
#pragma unroll
          for (int cf = 0; cf < 4; ++cf) {
            uint32_t d0 = pk_bf16(sv[cf][0], sv[cf][1]);
            uint32_t d1 = pk_bf16(sv[cf][2], sv[cf][3]);
            uint2 val = { d0, d1 };
            const int boff = (rowb + ((cf * 16 + hi * 4) << 1)) ^ swz;
            *(uint2*)((char*)&PT[w][0] + boff) = val;
          }
        }

#pragma unroll
        for (int ch = 0; ch < 2; ++ch) {
          const int boffp = ((lr << 7) + (ch * 64 + hi * 16)) ^ ((lr & 7) << 4);
          bf16x8 pa = *(const bf16x8*)((const char*)&PT[w][0] + boffp);
          __builtin_amdgcn_s_setprio(1);
#pragma unroll
          for (int df = 0; df < 4; ++df) {
            const int vrow = df * 16 + lr;
            const int boffv = ((vrow << 7) + ((ch * 32 + hi * 8) << 1)) ^ ((vrow & 7) << 4);
            bf16x8 vf = *(const bf16x8*)((const char*)vsb + boffv);
            acc[df] = __builtin_amdgcn_mfma_f32_16x16x32_bf16(pa, vf, acc[df], 0, 0, 0);
          }
          __builtin_amdgcn_s_setprio(0);
        }
      }
      if (kt + 1 < nkt) {
        char* kb_ = (char*)&Ks[buf ^ 1][0];
        char* vb_ = (char*)&Vts[buf ^ 1][0];
        *(bf16x8*)(kb_ + kw0) = sk0;
        *(bf16x8*)(kb_ + kw1) = sk1;
        *(bf16x8*)(vb_ + kw0) = sv0;
        *(bf16x8*)(vb_ + kw1) = sv1;
        if (kt + 2 < nkt) {
          sk0 = *(const bf16x8*)(kg0 + (size_t)(kt + 2) * 4096);
          sk1 = *(const bf16x8*)(kg1 + (size_t)(kt + 2) * 4096);
          sv0 = *(const bf16x8*)(vg0 + (kt + 2) * 64);
          sv1 = *(const bf16x8*)(vg1 + (kt + 2) * 64);
        }
        asm volatile("s_waitcnt lgkmcnt(0)" ::: "memory");
        __builtin_amdgcn_sched_barrier(0);
        __builtin_amdgcn_s_barrier();
      }
      buf ^= 1;
    }

    float lf = lsum;
    lf += __shfl_xor(lf, 16);
    lf += __shfl_xor(lf, 32);
#pragma unroll
    for (int r = 0; r < 4; ++r) {
      const float inv = 1.0f / __shfl(lf, hi * 4 + r);
      const int s = q0 + w * 16 + hi * 4 + r;
      const size_t rowbase = ((size_t)(b * 2048 + s)) * 1024 + h * 64;
#pragma unroll
      for (int df = 0; df < 4; ++df)
        ctx[rowbase + df * 16 + lr] = f2bf(acc[df][r] * inv);
    }
  }
}

extern "C" void kernel_launch(void* const* d_in, const int* in_sizes, int n_in,
                              void* d_out, int out_size, void* d_ws, size_t ws_size,
                              hipStream_t stream) {
  const float* x  = (const float*)d_in[0];
  const float* Wq = (const float*)d_in[1];
  const float* Wk = (const float*)d_in[2];
  const float* Wv = (const float*)d_in[3];
  const float* Wo = (const float*)d_in[4];
  const float* bo = (const float*)d_in[5];
  float* out = (float*)d_out;

  const size_t MB = 1ull << 20;
  if (ws_size < 48 * MB) return;  // loud failure instead of corruption
  char* ws = (char*)d_ws;
  u16* xb   = (u16*)(ws);             // [4096][1024]
  u16* Wcat = (u16*)(ws + 8 * MB);    // [3072][1024]  (Wq|Wk|Wv)
  u16* Wob  = (u16*)(ws + 14 * MB);   // [1024][1024]
  u16* Qb   = (u16*)(ws + 16 * MB);   // [B,H,S,DH]  (pre-scaled)
  u16* Kb   = (u16*)(ws + 24 * MB);   // [B,H,S,DH]
  u16* Vtb  = (u16*)(ws + 32 * MB);   // [B,H,DH,S]
  u16* ctxb = (u16*)(ws + 40 * MB);   // [4096][1024]

  hipLaunchKernelGGL(cast_all, dim3(4096), dim3(256), 0, stream,
                     x, Wq, Wk, Wv, Wo, xb, Wcat, Wob);
  hipLaunchKernelGGL((gemm_bt<0>), dim3(24, 32), dim3(256), 0, stream,
                     xb, Wcat, 4096, 3072, 1024, Qb, Kb, Vtb, (float*)nullptr, (const float*)nullptr);
  hipLaunchKernelGGL(flash_attn, dim3(16, 32), dim3(256), 0, stream, Qb, Kb, Vtb, ctxb);
  hipLaunchKernelGGL((gemm_bt<1>), dim3(8, 32), dim3(256), 0, stream,
                     ctxb, Wob, 4096, 1024, 1024,
                     (u16*)nullptr, (u16*)nullptr, (u16*)nullptr, out, bo);
}

// Round 18
// 132.294 us; speedup vs baseline: 1.0410x; 1.0410x over previous
//
#include <hip/hip_runtime.h>
#include <stdint.h>

typedef unsigned short u16;
typedef __attribute__((ext_vector_type(8))) short bf16x8;
typedef __attribute__((ext_vector_type(4))) float f32x4;
typedef __attribute__((ext_vector_type(4))) unsigned short u16x4;

__device__ __forceinline__ u16 f2bf(float f) {
  union { float f; uint32_t u; } c; c.f = f;
  uint32_t u = c.u;
  return (u16)((u + 0x7fffu + ((u >> 16) & 1u)) >> 16);
}

__device__ __forceinline__ uint32_t pk_bf16(float lo, float hi) {
  uint32_t d;
  asm("v_cvt_pk_bf16_f32 %0, %1, %2" : "=v"(d) : "v"(lo), "v"(hi));
  return d;
}

__device__ __forceinline__ void gload_lds16(const u16* g, u16* l) {
  __builtin_amdgcn_global_load_lds(
      (const __attribute__((address_space(1))) void*)g,
      (__attribute__((address_space(3))) void*)l, 16, 0, 0);
}

// one launch: x -> xb, Wq|Wk|Wv -> Wcat, Wo -> Wob
__global__ void cast_all(const float* __restrict__ x,
                         const float* __restrict__ Wq, const float* __restrict__ Wk,
                         const float* __restrict__ Wv, const float* __restrict__ Wo,
                         u16* __restrict__ xb, u16* __restrict__ Wcat, u16* __restrict__ Wob) {
  int i = (blockIdx.x * blockDim.x + threadIdx.x) * 4;
  const int stride = gridDim.x * blockDim.x * 4;
  for (; i < 8388608; i += stride) {
    const float* src;
    u16* dst;
    if (i < 4194304) {
      src = x + i; dst = xb + i;
    } else {
      const int j = i - 4194304;
      const int sel = j >> 20, off = j & 1048575;
      src = ((sel == 0) ? Wq : (sel == 1) ? Wk : (sel == 2) ? Wv : Wo) + off;
      dst = (sel < 3) ? (Wcat + j) : (Wob + off);
    }
    float4 v = *reinterpret_cast<const float4*>(src);
    u16x4 o = { f2bf(v.x), f2bf(v.y), f2bf(v.z), f2bf(v.w) };
    *reinterpret_cast<u16x4*>(dst) = o;
  }
}

#define QSCALE 0.18033688011112042f  /* 1/sqrt(64) * log2(e) */

// C = A @ B^T.  128x128 tile, BK=32, LDS double-buffer with counted vmcnt.
// EPI 0: scatter Q(pre-scaled)/K (n0 < 2048 only; V handled by gemm_vt).
// EPI 1: fp32 out + bias.
template<int EPI>
__global__ __launch_bounds__(256) void gemm_bt(
    const u16* __restrict__ A, const u16* __restrict__ B,
    int M, int N, int K,
    u16* __restrict__ o0, u16* __restrict__ o1,
    float* __restrict__ fo, const float* __restrict__ bias)
{
  __shared__ __align__(16) u16 As[2][128 * 32];
  __shared__ __align__(16) u16 Bs[2][128 * 32];
  const int tid = threadIdx.x;
  const int w = tid >> 6, l = tid & 63;
  const int m0 = blockIdx.y * 128, n0 = blockIdx.x * 128;
  const int arow = (w << 4) + (l >> 2);
  const int acol = (l & 3) << 3;
  const int wr = (w >> 1) << 6, wc = (w & 1) << 6;
  const int lr = l & 15, hi = l >> 4;
  const int lk = hi << 3;
  f32x4 acc[4][4] = {};

  const u16* Ap = A + (size_t)(m0 + arow) * K + acol;
  const u16* Bp = B + (size_t)(n0 + arow) * K + acol;
  const int so = (w << 9);

  gload_lds16(Ap, &As[0][so]);
  gload_lds16(Ap + (size_t)64 * K, &As[0][so + 2048]);
  gload_lds16(Bp, &Bs[0][so]);
  gload_lds16(Bp + (size_t)64 * K, &Bs[0][so + 2048]);

  int buf = 0;
  for (int k0 = 0; k0 < K; k0 += 32) {
    if (k0 + 32 < K) {
      const int nb = buf ^ 1;
      gload_lds16(Ap + k0 + 32, &As[nb][so]);
      gload_lds16(Ap + (size_t)64 * K + k0 + 32, &As[nb][so + 2048]);
      gload_lds16(Bp + k0 + 32, &Bs[nb][so]);
      gload_lds16(Bp + (size_t)64 * K + k0 + 32, &Bs[nb][so + 2048]);
      asm volatile("s_waitcnt vmcnt(4)" ::: "memory");
    } else {
      asm volatile("s_waitcnt vmcnt(0)" ::: "memory");
    }
    __builtin_amdgcn_sched_barrier(0);
    __builtin_amdgcn_s_barrier();
    bf16x8 af[4], bfr[4];
#pragma unroll
    for (int m = 0; m < 4; ++m)
      af[m] = *(const bf16x8*)(&As[buf][0] + (wr + m * 16 + lr) * 32 + lk);
#pragma unroll
    for (int n = 0; n < 4; ++n)
      bfr[n] = *(const bf16x8*)(&Bs[buf][0] + (wc + n * 16 + lr) * 32 + lk);
    __builtin_amdgcn_s_setprio(1);
#pragma unroll
    for (int m = 0; m < 4; ++m)
#pragma unroll
      for (int n = 0; n < 4; ++n)
        acc[m][n] = __builtin_amdgcn_mfma_f32_16x16x32_bf16(af[m], bfr[n], acc[m][n], 0, 0, 0);
    __builtin_amdgcn_s_setprio(0);
    __builtin_amdgcn_s_barrier();
    buf ^= 1;
  }

#pragma unroll
  for (int mm = 0; mm < 4; ++mm) {
#pragma unroll
    for (int nn = 0; nn < 4; ++nn) {
      const int ng = n0 + wc + nn * 16 + lr;
      if (EPI == 0) {
        const int mat = ng >> 10;
        const int col = ng & 1023;
        const int h = col >> 6, dh = col & 63;
#pragma unroll
        for (int r = 0; r < 4; ++r) {
          const int mg = m0 + wr + mm * 16 + (hi << 2) + r;
          const int b = mg >> 11, s = mg & 2047;
          if (mat == 0)
            o0[(((size_t)(b * 16 + h)) * 2048 + s) * 64 + dh] = f2bf(acc[mm][nn][r] * QSCALE);
          else
            o1[(((size_t)(b * 16 + h)) * 2048 + s) * 64 + dh] = f2bf(acc[mm][nn][r]);
        }
      } else {
        const float bv = bias[ng];
#pragma unroll
        for (int r = 0; r < 4; ++r) {
          const int mg = m0 + wr + mm * 16 + (hi << 2) + r;
          fo[(size_t)mg * N + ng] = acc[mm][nn][r] + bv;
        }
      }
    }
  }
}

// V-projection GEMM, compile-time specialized: computes (Wv_rows @ x_rows^T)
// via operand-swapped MFMA so accumulators hold the TRANSPOSED product;
// Vt [B,H,DH,S] store is then s-contiguous per lane (32B-coalesced).
// Same staging/pipeline as gemm_bt; values bit-identical to the unswapped
// product (same dot products, same instruction).
__global__ __launch_bounds__(256) void gemm_vt(
    const u16* __restrict__ A, const u16* __restrict__ B,  // A=xb, B=Wv(bf16)
    u16* __restrict__ o2)
{
  const int K = 1024;
  __shared__ __align__(16) u16 As[2][128 * 32];
  __shared__ __align__(16) u16 Bs[2][128 * 32];
  const int tid = threadIdx.x;
  const int w = tid >> 6, l = tid & 63;
  const int m0 = blockIdx.y * 128, n0 = blockIdx.x * 128;
  const int arow = (w << 4) + (l >> 2);
  const int acol = (l & 3) << 3;
  const int wr = (w >> 1) << 6, wc = (w & 1) << 6;
  const int lr = l & 15, hi = l >> 4;
  const int lk = hi << 3;
  f32x4 acc[4][4] = {};

  const u16* Ap = A + (size_t)(m0 + arow) * K + acol;
  const u16* Bp = B + (size_t)(n0 + arow) * K + acol;
  const int so = (w << 9);

  gload_lds16(Ap, &As[0][so]);
  gload_lds16(Ap + (size_t)64 * K, &As[0][so + 2048]);
  gload_lds16(Bp, &Bs[0][so]);
  gload_lds16(Bp + (size_t)64 * K, &Bs[0][so + 2048]);

  int buf = 0;
  for (int k0 = 0; k0 < K; k0 += 32) {
    if (k0 + 32 < K) {
      const int nb = buf ^ 1;
      gload_lds16(Ap + k0 + 32, &As[nb][so]);
      gload_lds16(Ap + (size_t)64 * K + k0 + 32, &As[nb][so + 2048]);
      gload_lds16(Bp + k0 + 32, &Bs[nb][so]);
      gload_lds16(Bp + (size_t)64 * K + k0 + 32, &Bs[nb][so + 2048]);
      asm volatile("s_waitcnt vmcnt(4)" ::: "memory");
    } else {
      asm volatile("s_waitcnt vmcnt(0)" ::: "memory");
    }
    __builtin_amdgcn_sched_barrier(0);
    __builtin_amdgcn_s_barrier();
    bf16x8 af[4], bfr[4];
#pragma unroll
    for (int m = 0; m < 4; ++m)
      af[m] = *(const bf16x8*)(&As[buf][0] + (wr + m * 16 + lr) * 32 + lk);
#pragma unroll
    for (int n = 0; n < 4; ++n)
      bfr[n] = *(const bf16x8*)(&Bs[buf][0] + (wc + n * 16 + lr) * 32 + lk);
    __builtin_amdgcn_s_setprio(1);
#pragma unroll
    for (int m = 0; m < 4; ++m)
#pragma unroll
      for (int n = 0; n < 4; ++n)
        acc[m][n] = __builtin_amdgcn_mfma_f32_16x16x32_bf16(bfr[n], af[m], acc[m][n], 0, 0, 0);
    __builtin_amdgcn_s_setprio(0);
    __builtin_amdgcn_s_barrier();
    buf ^= 1;
  }

  // acc[mm][nn] = (B@A^T) sub-tile: row = n_local (dh), col = m_local (s)
  const int b = m0 >> 11, s0 = m0 & 2047;
#pragma unroll
  for (int mm = 0; mm < 4; ++mm) {
#pragma unroll
    for (int nn = 0; nn < 4; ++nn) {
      const int ml = wr + mm * 16 + lr;         // s offset (contiguous per lane)
      const int nlb = n0 + wc + nn * 16 + (hi << 2); // dh row base (+r)
#pragma unroll
      for (int r = 0; r < 4; ++r) {
        const int col = nlb + r;
        const int h = col >> 6, dh = col & 63;
        o2[(((size_t)(b * 16 + h)) * 64 + dh) * 2048 + s0 + ml] = f2bf(acc[mm][nn][r]);
      }
    }
  }
}

// Flash attention, causal.  UNIFORM-WORK pairing: grid (16,32); block p
// processes q-tile p (p+1 kv-phases) then q-tile 31-p (32-p phases) with
// the same 4 waves -> every block runs exactly 33 phases.  Inner pipeline:
// K/V reg-staged (global->reg, ds_write to buf^1 at phase end), ONE
// barrier per phase, loads issued 2 tiles ahead; swapped QK^T -> in-lane
// exp2 softmax; per-wave PT bounce.
__global__ __launch_bounds__(256) void flash_attn(
    const u16* __restrict__ Qg, const u16* __restrict__ Kg,
    const u16* __restrict__ Vtg, u16* __restrict__ ctx)
{
  __shared__ __align__(16) u16 Ks[2][4096];
  __shared__ __align__(16) u16 Vts[2][4096];
  __shared__ __align__(16) u16 PT[4][1024];
  const int tid = threadIdx.x, w = tid >> 6, l = tid & 63;
  const int lr = l & 15, hi = l >> 4;
  const int p = blockIdx.x;          // pair index [0,16)
  const int bh = blockIdx.y;
  const size_t kqbase = (size_t)bh * (2048 * 64);
  const int h = bh & 15, b = bh >> 4;

  const int c0 = w * 128 + l;
  const int c1 = c0 + 64;
  const int r0 = c0 >> 3, p0 = c0 & 7;
  const int r1 = c1 >> 3, p1 = c1 & 7;
  const u16* kg0 = Kg + kqbase + r0 * 64 + p0 * 8;
  const u16* kg1 = Kg + kqbase + r1 * 64 + p1 * 8;
  const u16* vg0 = Vtg + kqbase + (size_t)r0 * 2048 + p0 * 8;
  const u16* vg1 = Vtg + kqbase + (size_t)r1 * 2048 + p1 * 8;
  const int kw0 = (r0 << 7) + ((p0 ^ (r0 & 7)) << 4);
  const int kw1 = (r1 << 7) + ((p1 ^ (r1 & 7)) << 4);

  for (int seg = 0; seg < 2; ++seg) {
    const int qt = seg ? (31 - p) : p;
    const int q0 = qt * 64;
    const int nkt = qt + 1;
    const int qg = q0 + w * 16 + lr;

    if (seg) __builtin_amdgcn_s_barrier();   // protect LDS reuse across segments

    bf16x8 qf[2];
    {
      const u16* qp = Qg + kqbase + (size_t)(q0 + w * 16 + lr) * 64 + hi * 8;
      qf[0] = *(const bf16x8*)(qp);
      qf[1] = *(const bf16x8*)(qp + 32);
    }

    f32x4 acc[4] = {};
    float lsum = 0.0f;

    // prologue: tile 0 -> regs -> buf0; issue tile 1 loads
    bf16x8 sk0 = *(const bf16x8*)kg0;
    bf16x8 sk1 = *(const bf16x8*)kg1;
    bf16x8 sv0 = *(const bf16x8*)vg0;
    bf16x8 sv1 = *(const bf16x8*)vg1;
    *(bf16x8*)((char*)&Ks[0][0] + kw0) = sk0;
    *(bf16x8*)((char*)&Ks[0][0] + kw1) = sk1;
    *(bf16x8*)((char*)&Vts[0][0] + kw0) = sv0;
    *(bf16x8*)((char*)&Vts[0][0] + kw1) = sv1;
    if (nkt > 1) {
      sk0 = *(const bf16x8*)(kg0 + 4096);
      sk1 = *(const bf16x8*)(kg1 + 4096);
      sv0 = *(const bf16x8*)(vg0 + 64);
      sv1 = *(const bf16x8*)(vg1 + 64);
    }
    asm volatile("s_waitcnt lgkmcnt(0)" ::: "memory");
    __builtin_amdgcn_sched_barrier(0);
    __builtin_amdgcn_s_barrier();

    int buf = 0;
    for (int kt = 0; kt < nkt; ++kt) {
      {
        const u16* ksb = &Ks[buf][0];
        const u16* vsb = &Vts[buf][0];
        f32x4 sv[4];
        __builtin_amdgcn_s_setprio(1);
#pragma unroll
        for (int cf = 0; cf < 4; ++cf) {
          f32x4 z = {};
#pragma unroll
          for (int ch = 0; ch < 2; ++ch) {
            const int krow = cf * 16 + lr;
            const int boff = ((krow << 7) + ((ch * 32 + hi * 8) << 1)) ^ ((krow & 7) << 4);
            bf16x8 kf = *(const bf16x8*)((const char*)ksb + boff);
            z = __builtin_amdgcn_mfma_f32_16x16x32_bf16(kf, qf[ch], z, 0, 0, 0);
          }
          sv[cf] = z;
        }
        __builtin_amdgcn_s_setprio(0);

        const bool diag = (kt == nkt - 1);
        const int kb = kt * 64 + hi * 4;
        float ts = 0.0f;
#pragma unroll
        for (int cf = 0; cf < 4; ++cf) {
          f32x4 pv;
#pragma unroll
          for (int r = 0; r < 4; ++r) {
            float s = sv[cf][r];
            if (diag && (kb + cf * 16 + r) > qg) s = -1e30f;
            pv[r] = exp2f(s);
          }
          sv[cf] = pv;
          ts += (pv[0] + pv[1]) + (pv[2] + pv[3]);
        }
        lsum += ts;

        {
          const int rowb = lr << 7;
          const int swz = (lr & 7) << 4;
#pragma unroll
          for (int cf = 0; cf < 4; ++cf) {
            uint32_t d0 = pk_bf16(sv[cf][0], sv[cf][1]);
            uint32_t d1 = pk_bf16(sv[cf][2], sv[cf][3]);
            uint2 val = { d0, d1 };
            const int boff = (rowb + ((cf * 16 + hi * 4) << 1)) ^ swz;
            *(uint2*)((char*)&PT[w][0] + boff) = val;
          }
        }

#pragma unroll
        for (int ch = 0; ch < 2; ++ch) {
          const int boffp = ((lr << 7) + (ch * 64 + hi * 16)) ^ ((lr & 7) << 4);
          bf16x8 pa = *(const bf16x8*)((const char*)&PT[w][0] + boffp);
          __builtin_amdgcn_s_setprio(1);
#pragma unroll
          for (int df = 0; df < 4; ++df) {
            const int vrow = df * 16 + lr;
            const int boffv = ((vrow << 7) + ((ch * 32 + hi * 8) << 1)) ^ ((vrow & 7) << 4);
            bf16x8 vf = *(const bf16x8*)((const char*)vsb + boffv);
            acc[df] = __builtin_amdgcn_mfma_f32_16x16x32_bf16(pa, vf, acc[df], 0, 0, 0);
          }
          __builtin_amdgcn_s_setprio(0);
        }
      }
      if (kt + 1 < nkt) {
        char* kb_ = (char*)&Ks[buf ^ 1][0];
        char* vb_ = (char*)&Vts[buf ^ 1][0];
        *(bf16x8*)(kb_ + kw0) = sk0;
        *(bf16x8*)(kb_ + kw1) = sk1;
        *(bf16x8*)(vb_ + kw0) = sv0;
        *(bf16x8*)(vb_ + kw1) = sv1;
        if (kt + 2 < nkt) {
          sk0 = *(const bf16x8*)(kg0 + (size_t)(kt + 2) * 4096);
          sk1 = *(const bf16x8*)(kg1 + (size_t)(kt + 2) * 4096);
          sv0 = *(const bf16x8*)(vg0 + (kt + 2) * 64);
          sv1 = *(const bf16x8*)(vg1 + (kt + 2) * 64);
        }
        asm volatile("s_waitcnt lgkmcnt(0)" ::: "memory");
        __builtin_amdgcn_sched_barrier(0);
        __builtin_amdgcn_s_barrier();
      }
      buf ^= 1;
    }

    float lf = lsum;
    lf += __shfl_xor(lf, 16);
    lf += __shfl_xor(lf, 32);
#pragma unroll
    for (int r = 0; r < 4; ++r) {
      const float inv = 1.0f / __shfl(lf, hi * 4 + r);
      const int s = q0 + w * 16 + hi * 4 + r;
      const size_t rowbase = ((size_t)(b * 2048 + s)) * 1024 + h * 64;
#pragma unroll
      for (int df = 0; df < 4; ++df)
        ctx[rowbase + df * 16 + lr] = f2bf(acc[df][r] * inv);
    }
  }
}

extern "C" void kernel_launch(void* const* d_in, const int* in_sizes, int n_in,
                              void* d_out, int out_size, void* d_ws, size_t ws_size,
                              hipStream_t stream) {
  const float* x  = (const float*)d_in[0];
  const float* Wq = (const float*)d_in[1];
  const float* Wk = (const float*)d_in[2];
  const float* Wv = (const float*)d_in[3];
  const float* Wo = (const float*)d_in[4];
  const float* bo = (const float*)d_in[5];
  float* out = (float*)d_out;

  const size_t MB = 1ull << 20;
  if (ws_size < 48 * MB) return;  // loud failure instead of corruption
  char* ws = (char*)d_ws;
  u16* xb   = (u16*)(ws);             // [4096][1024]
  u16* Wcat = (u16*)(ws + 8 * MB);    // [3072][1024]  (Wq|Wk|Wv)
  u16* Wob  = (u16*)(ws + 14 * MB);   // [1024][1024]
  u16* Qb   = (u16*)(ws + 16 * MB);   // [B,H,S,DH]  (pre-scaled)
  u16* Kb   = (u16*)(ws + 24 * MB);   // [B,H,S,DH]
  u16* Vtb  = (u16*)(ws + 32 * MB);   // [B,H,DH,S]
  u16* ctxb = (u16*)(ws + 40 * MB);   // [4096][1024]

  hipLaunchKernelGGL(cast_all, dim3(4096), dim3(256), 0, stream,
                     x, Wq, Wk, Wv, Wo, xb, Wcat, Wob);
  hipLaunchKernelGGL((gemm_bt<0>), dim3(16, 32), dim3(256), 0, stream,
                     xb, Wcat, 4096, 2048, 1024, Qb, Kb, (float*)nullptr, (const float*)nullptr);
  hipLaunchKernelGGL(gemm_vt, dim3(8, 32), dim3(256), 0, stream,
                     xb, Wcat + 2097152, Vtb);
  hipLaunchKernelGGL(flash_attn, dim3(16, 32), dim3(256), 0, stream, Qb, Kb, Vtb, ctxb);
  hipLaunchKernelGGL((gemm_bt<1>), dim3(8, 32), dim3(256), 0, stream,
                     ctxb, Wob, 4096, 1024, 1024,
                     (u16*)nullptr, (u16*)nullptr, out, bo);
}

// Round 21
// 124.603 us; speedup vs baseline: 1.1053x; 1.0617x over previous
//
#include <hip/hip_runtime.h>
#include <stdint.h>

typedef unsigned short u16;
typedef __attribute__((ext_vector_type(8))) short bf16x8;
typedef __attribute__((ext_vector_type(4))) float f32x4;
typedef __attribute__((ext_vector_type(4))) unsigned short u16x4;

__device__ __forceinline__ u16 f2bf(float f) {
  union { float f; uint32_t u; } c; c.f = f;
  uint32_t u = c.u;
  return (u16)((u + 0x7fffu + ((u >> 16) & 1u)) >> 16);
}

__device__ __forceinline__ uint32_t pk_bf16(float lo, float hi) {
  uint32_t d;
  asm("v_cvt_pk_bf16_f32 %0, %1, %2" : "=v"(d) : "v"(lo), "v"(hi));
  return d;
}

__device__ __forceinline__ void gload_lds16(const u16* g, u16* l) {
  __builtin_amdgcn_global_load_lds(
      (const __attribute__((address_space(1))) void*)g,
      (__attribute__((address_space(3))) void*)l, 16, 0, 0);
}

// one launch: x -> xb, Wq|Wk|Wv -> Wcat, Wo -> Wob
__global__ void cast_all(const float* __restrict__ x,
                         const float* __restrict__ Wq, const float* __restrict__ Wk,
                         const float* __restrict__ Wv, const float* __restrict__ Wo,
                         u16* __restrict__ xb, u16* __restrict__ Wcat, u16* __restrict__ Wob) {
  int i = (blockIdx.x * blockDim.x + threadIdx.x) * 4;
  const int stride = gridDim.x * blockDim.x * 4;
  for (; i < 8388608; i += stride) {
    const float* src;
    u16* dst;
    if (i < 4194304) {
      src = x + i; dst = xb + i;
    } else {
      const int j = i - 4194304;
      const int sel = j >> 20, off = j & 1048575;
      src = ((sel == 0) ? Wq : (sel == 1) ? Wk : (sel == 2) ? Wv : Wo) + off;
      dst = (sel < 3) ? (Wcat + j) : (Wob + off);
    }
    float4 v = *reinterpret_cast<const float4*>(src);
    u16x4 o = { f2bf(v.x), f2bf(v.y), f2bf(v.z), f2bf(v.w) };
    *reinterpret_cast<u16x4*>(dst) = o;
  }
}

#define QSCALE 0.18033688011112042f  /* 1/sqrt(64) * log2(e) */

// C = A @ B^T.  128x128 tile, BK=32, LDS double-buffer with counted vmcnt.
// LDS bank-conflict fix (rule 21): dest linear, global source 16B-slot
// pre-swizzled with slot ^= (row>>1)&3; fragment reads apply the same XOR.
// Read conflict drops 8-way -> 2-way (free).  Values bit-identical.
// EPI 0: scatter Q(pre-scaled)/K/Vt.  EPI 1: fp32 out + bias.
template<int EPI>
__global__ __launch_bounds__(256) void gemm_bt(
    const u16* __restrict__ A, const u16* __restrict__ B,
    int M, int N, int K,
    u16* __restrict__ o0, u16* __restrict__ o1, u16* __restrict__ o2,
    float* __restrict__ fo, const float* __restrict__ bias)
{
  __shared__ __align__(16) u16 As[2][128 * 32];
  __shared__ __align__(16) u16 Bs[2][128 * 32];
  const int tid = threadIdx.x;
  const int w = tid >> 6, l = tid & 63;
  const int m0 = blockIdx.y * 128, n0 = blockIdx.x * 128;
  const int arow = (w << 4) + (l >> 2);
  const int aslot = (l & 3) ^ ((arow >> 1) & 3);   // pre-swizzled source slot
  const int acol = aslot << 3;
  const int wr = (w >> 1) << 6, wc = (w & 1) << 6;
  const int lr = l & 15, hi = l >> 4;
  f32x4 acc[4][4] = {};

  const u16* Ap = A + (size_t)(m0 + arow) * K + acol;
  const u16* Bp = B + (size_t)(n0 + arow) * K + acol;
  const int so = (w << 9);

  gload_lds16(Ap, &As[0][so]);
  gload_lds16(Ap + (size_t)64 * K, &As[0][so + 2048]);
  gload_lds16(Bp, &Bs[0][so]);
  gload_lds16(Bp + (size_t)64 * K, &Bs[0][so + 2048]);

  // fragment read byte offsets (swizzled to match the staged layout)
  int aoff[4], boff[4];
#pragma unroll
  for (int m = 0; m < 4; ++m) {
    const int row = wr + m * 16 + lr;
    aoff[m] = row * 64 + ((hi ^ ((row >> 1) & 3)) << 4);
  }
#pragma unroll
  for (int n = 0; n < 4; ++n) {
    const int row = wc + n * 16 + lr;
    boff[n] = row * 64 + ((hi ^ ((row >> 1) & 3)) << 4);
  }

  int buf = 0;
  for (int k0 = 0; k0 < K; k0 += 32) {
    if (k0 + 32 < K) {
      const int nb = buf ^ 1;
      gload_lds16(Ap + k0 + 32, &As[nb][so]);
      gload_lds16(Ap + (size_t)64 * K + k0 + 32, &As[nb][so + 2048]);
      gload_lds16(Bp + k0 + 32, &Bs[nb][so]);
      gload_lds16(Bp + (size_t)64 * K + k0 + 32, &Bs[nb][so + 2048]);
      asm volatile("s_waitcnt vmcnt(4)" ::: "memory");
    } else {
      asm volatile("s_waitcnt vmcnt(0)" ::: "memory");
    }
    __builtin_amdgcn_sched_barrier(0);
    __builtin_amdgcn_s_barrier();
    bf16x8 af[4], bfr[4];
#pragma unroll
    for (int m = 0; m < 4; ++m)
      af[m] = *(const bf16x8*)((const char*)&As[buf][0] + aoff[m]);
#pragma unroll
    for (int n = 0; n < 4; ++n)
      bfr[n] = *(const bf16x8*)((const char*)&Bs[buf][0] + boff[n]);
    __builtin_amdgcn_s_setprio(1);
#pragma unroll
    for (int m = 0; m < 4; ++m)
#pragma unroll
      for (int n = 0; n < 4; ++n)
        acc[m][n] = __builtin_amdgcn_mfma_f32_16x16x32_bf16(af[m], bfr[n], acc[m][n], 0, 0, 0);
    __builtin_amdgcn_s_setprio(0);
    __builtin_amdgcn_s_barrier();
    buf ^= 1;
  }

#pragma unroll
  for (int mm = 0; mm < 4; ++mm) {
#pragma unroll
    for (int nn = 0; nn < 4; ++nn) {
      const int ng = n0 + wc + nn * 16 + lr;
      if (EPI == 0) {
        const int mat = ng >> 10;
        const int col = ng & 1023;
        const int h = col >> 6, dh = col & 63;
#pragma unroll
        for (int r = 0; r < 4; ++r) {
          const int mg = m0 + wr + mm * 16 + (hi << 2) + r;
          const int b = mg >> 11, s = mg & 2047;
          if (mat == 0)
            o0[(((size_t)(b * 16 + h)) * 2048 + s) * 64 + dh] = f2bf(acc[mm][nn][r] * QSCALE);
          else if (mat == 1)
            o1[(((size_t)(b * 16 + h)) * 2048 + s) * 64 + dh] = f2bf(acc[mm][nn][r]);
          else
            o2[(((size_t)(b * 16 + h)) * 64 + dh) * 2048 + s] = f2bf(acc[mm][nn][r]);
        }
      } else {
        const float bv = bias[ng];
#pragma unroll
        for (int r = 0; r < 4; ++r) {
          const int mg = m0 + wr + mm * 16 + (hi << 2) + r;
          fo[(size_t)mg * N + ng] = acc[mm][nn][r] + bv;
        }
      }
    }
  }
}

// Flash attention, causal.  UNIFORM-WORK pairing: grid (16,32); block p
// processes q-tile p (p+1 kv-phases) then q-tile 31-p (32-p phases) with
// the same 4 waves -> every block runs exactly 33 phases.  Inner pipeline:
// K/V reg-staged (global->reg, ds_write to buf^1 at phase end), ONE
// barrier per phase, loads issued 2 tiles ahead; swapped QK^T -> in-lane
// exp2 softmax; per-wave PT bounce.
__global__ __launch_bounds__(256) void flash_attn(
    const u16* __restrict__ Qg, const u16* __restrict__ Kg,
    const u16* __restrict__ Vtg, u16* __restrict__ ctx)
{
  __shared__ __align__(16) u16 Ks[2][4096];
  __shared__ __align__(16) u16 Vts[2][4096];
  __shared__ __align__(16) u16 PT[4][1024];
  const int tid = threadIdx.x, w = tid >> 6, l = tid & 63;
  const int lr = l & 15, hi = l >> 4;
  const int p = blockIdx.x;          // pair index [0,16)
  const int bh = blockIdx.y;
  const size_t kqbase = (size_t)bh * (2048 * 64);
  const int h = bh & 15, b = bh >> 4;

  const int c0 = w * 128 + l;
  const int c1 = c0 + 64;
  const int r0 = c0 >> 3, p0 = c0 & 7;
  const int r1 = c1 >> 3, p1 = c1 & 7;
  const u16* kg0 = Kg + kqbase + r0 * 64 + p0 * 8;
  const u16* kg1 = Kg + kqbase + r1 * 64 + p1 * 8;
  const u16* vg0 = Vtg + kqbase + (size_t)r0 * 2048 + p0 * 8;
  const u16* vg1 = Vtg + kqbase + (size_t)r1 * 2048 + p1 * 8;
  const int kw0 = (r0 << 7) + ((p0 ^ (r0 & 7)) << 4);
  const int kw1 = (r1 << 7) + ((p1 ^ (r1 & 7)) << 4);

  for (int seg = 0; seg < 2; ++seg) {
    const int qt = seg ? (31 - p) : p;
    const int q0 = qt * 64;
    const int nkt = qt + 1;
    const int qg = q0 + w * 16 + lr;

    if (seg) __builtin_amdgcn_s_barrier();   // protect LDS reuse across segments

    bf16x8 qf[2];
    {
      const u16* qp = Qg + kqbase + (size_t)(q0 + w * 16 + lr) * 64 + hi * 8;
      qf[0] = *(const bf16x8*)(qp);
      qf[1] = *(const bf16x8*)(qp + 32);
    }

    f32x4 acc[4] = {};
    float lsum = 0.0f;

    // prologue: tile 0 -> regs -> buf0; issue tile 1 loads
    bf16x8 sk0 = *(const bf16x8*)kg0;
    bf16x8 sk1 = *(const bf16x8*)kg1;
    bf16x8 sv0 = *(const bf16x8*)vg0;
    bf16x8 sv1 = *(const bf16x8*)vg1;
    *(bf16x8*)((char*)&Ks[0][0] + kw0) = sk0;
    *(bf16x8*)((char*)&Ks[0][0] + kw1) = sk1;
    *(bf16x8*)((char*)&Vts[0][0] + kw0) = sv0;
    *(bf16x8*)((char*)&Vts[0][0] + kw1) = sv1;
    if (nkt > 1) {
      sk0 = *(const bf16x8*)(kg0 + 4096);
      sk1 = *(const bf16x8*)(kg1 + 4096);
      sv0 = *(const bf16x8*)(vg0 + 64);
      sv1 = *(const bf16x8*)(vg1 + 64);
    }
    asm volatile("s_waitcnt lgkmcnt(0)" ::: "memory");
    __builtin_amdgcn_sched_barrier(0);
    __builtin_amdgcn_s_barrier();

    int buf = 0;
    for (int kt = 0; kt < nkt; ++kt) {
      {
        const u16* ksb = &Ks[buf][0];
        const u16* vsb = &Vts[buf][0];
        f32x4 sv[4];
        __builtin_amdgcn_s_setprio(1);
#pragma unroll
        for (int cf = 0; cf < 4; ++cf) {
          f32x4 z = {};
#pragma unroll
          for (int ch = 0; ch < 2; ++ch) {
            const int krow = cf * 16 + lr;
            const int boff = ((krow << 7) + ((ch * 32 + hi * 8) << 1)) ^ ((krow & 7) << 4);
            bf16x8 kf = *(const bf16x8*)((const char*)ksb + boff);
            z = __builtin_amdgcn_mfma_f32_16x16x32_bf16(kf, qf[ch], z, 0, 0, 0);
          }
          sv[cf] = z;
        }
        __builtin_amdgcn_s_setprio(0);

        const bool diag = (kt == nkt - 1);
        const int kb = kt * 64 + hi * 4;
        float ts = 0.0f;
#pragma unroll
        for (int cf = 0; cf < 4; ++cf) {
          f32x4 pv;
#pragma unroll
          for (int r = 0; r < 4; ++r) {
            float s = sv[cf][r];
            if (diag && (kb + cf * 16 + r) > qg) s = -1e30f;
            pv[r] = exp2f(s);
          }
          sv[cf] = pv;
          ts += (pv[0] + pv[1]) + (pv[2] + pv[3]);
        }
        lsum += ts;

        {
          const int rowb = lr << 7;
          const int swz = (lr & 7) << 4;
#pragma unroll
          for (int cf = 0; cf < 4; ++cf) {
            uint32_t d0 = pk_bf16(sv[cf][0], sv[cf][1]);
            uint32_t d1 = pk_bf16(sv[cf][2], sv[cf][3]);
            uint2 val = { d0, d1 };
            const int boff = (rowb + ((cf * 16 + hi * 4) << 1)) ^ swz;
            *(uint2*)((char*)&PT[w][0] + boff) = val;
          }
        }

#pragma unroll
        for (int ch = 0; ch < 2; ++ch) {
          const int boffp = ((lr << 7) + (ch * 64 + hi * 16)) ^ ((lr & 7) << 4);
          bf16x8 pa = *(const bf16x8*)((const char*)&PT[w][0] + boffp);
          __builtin_amdgcn_s_setprio(1);
#pragma unroll
          for (int df = 0; df < 4; ++df) {
            const int vrow = df * 16 + lr;
            const int boffv = ((vrow << 7) + ((ch * 32 + hi * 8) << 1)) ^ ((vrow & 7) << 4);
            bf16x8 vf = *(const bf16x8*)((const char*)vsb + boffv);
            acc[df] = __builtin_amdgcn_mfma_f32_16x16x32_bf16(pa, vf, acc[df], 0, 0, 0);
          }
          __builtin_amdgcn_s_setprio(0);
        }
      }
      if (kt + 1 < nkt) {
        char* kb_ = (char*)&Ks[buf ^ 1][0];
        char* vb_ = (char*)&Vts[buf ^ 1][0];
        *(bf16x8*)(kb_ + kw0) = sk0;
        *(bf16x8*)(kb_ + kw1) = sk1;
        *(bf16x8*)(vb_ + kw0) = sv0;
        *(bf16x8*)(vb_ + kw1) = sv1;
        if (kt + 2 < nkt) {
          sk0 = *(const bf16x8*)(kg0 + (size_t)(kt + 2) * 4096);
          sk1 = *(const bf16x8*)(kg1 + (size_t)(kt + 2) * 4096);
          sv0 = *(const bf16x8*)(vg0 + (kt + 2) * 64);
          sv1 = *(const bf16x8*)(vg1 + (kt + 2) * 64);
        }
        asm volatile("s_waitcnt lgkmcnt(0)" ::: "memory");
        __builtin_amdgcn_sched_barrier(0);
        __builtin_amdgcn_s_barrier();
      }
      buf ^= 1;
    }

    float lf = lsum;
    lf += __shfl_xor(lf, 16);
    lf += __shfl_xor(lf, 32);
#pragma unroll
    for (int r = 0; r < 4; ++r) {
      const float inv = 1.0f / __shfl(lf, hi * 4 + r);
      const int s = q0 + w * 16 + hi * 4 + r;
      const size_t rowbase = ((size_t)(b * 2048 + s)) * 1024 + h * 64;
#pragma unroll
      for (int df = 0; df < 4; ++df)
        ctx[rowbase + df * 16 + lr] = f2bf(acc[df][r] * inv);
    }
  }
}

extern "C" void kernel_launch(void* const* d_in, const int* in_sizes, int n_in,
                              void* d_out, int out_size, void* d_ws, size_t ws_size,
                              hipStream_t stream) {
  const float* x  = (const float*)d_in[0];
  const float* Wq = (const float*)d_in[1];
  const float* Wk = (const float*)d_in[2];
  const float* Wv = (const float*)d_in[3];
  const float* Wo = (const float*)d_in[4];
  const float* bo = (const float*)d_in[5];
  float* out = (float*)d_out;

  const size_t MB = 1ull << 20;
  if (ws_size < 48 * MB) return;  // loud failure instead of corruption
  char* ws = (char*)d_ws;
  u16* xb   = (u16*)(ws);             // [4096][1024]
  u16* Wcat = (u16*)(ws + 8 * MB);    // [3072][1024]  (Wq|Wk|Wv)
  u16* Wob  = (u16*)(ws + 14 * MB);   // [1024][1024]
  u16* Qb   = (u16*)(ws + 16 * MB);   // [B,H,S,DH]  (pre-scaled)
  u16* Kb   = (u16*)(ws + 24 * MB);   // [B,H,S,DH]
  u16* Vtb  = (u16*)(ws + 32 * MB);   // [B,H,DH,S]
  u16* ctxb = (u16*)(ws + 40 * MB);   // [4096][1024]

  hipLaunchKernelGGL(cast_all, dim3(4096), dim3(256), 0, stream,
                     x, Wq, Wk, Wv, Wo, xb, Wcat, Wob);
  hipLaunchKernelGGL((gemm_bt<0>), dim3(24, 32), dim3(256), 0, stream,
                     xb, Wcat, 4096, 3072, 1024, Qb, Kb, Vtb, (float*)nullptr, (const float*)nullptr);
  hipLaunchKernelGGL(flash_attn, dim3(16, 32), dim3(256), 0, stream, Qb, Kb, Vtb, ctxb);
  hipLaunchKernelGGL((gemm_bt<1>), dim3(8, 32), dim3(256), 0, stream,
                     ctxb, Wob, 4096, 1024, 1024,
                     (u16*)nullptr, (u16*)nullptr, (u16*)nullptr, out, bo);
}

// Round 22
// 121.466 us; speedup vs baseline: 1.1339x; 1.0258x over previous
//
#include <hip/hip_runtime.h>
#include <stdint.h>

typedef unsigned short u16;
typedef __attribute__((ext_vector_type(8))) short bf16x8;
typedef __attribute__((ext_vector_type(4))) float f32x4;
typedef __attribute__((ext_vector_type(4))) unsigned short u16x4;

__device__ __forceinline__ u16 f2bf(float f) {
  union { float f; uint32_t u; } c; c.f = f;
  uint32_t u = c.u;
  return (u16)((u + 0x7fffu + ((u >> 16) & 1u)) >> 16);
}

__device__ __forceinline__ uint32_t pk_bf16(float lo, float hi) {
  uint32_t d;
  asm("v_cvt_pk_bf16_f32 %0, %1, %2" : "=v"(d) : "v"(lo), "v"(hi));
  return d;
}

__device__ __forceinline__ void gload_lds16(const u16* g, u16* l) {
  __builtin_amdgcn_global_load_lds(
      (const __attribute__((address_space(1))) void*)g,
      (__attribute__((address_space(3))) void*)l, 16, 0, 0);
}

// one launch: x -> xb, Wq|Wk|Wv -> Wcat, Wo -> Wob
__global__ void cast_all(const float* __restrict__ x,
                         const float* __restrict__ Wq, const float* __restrict__ Wk,
                         const float* __restrict__ Wv, const float* __restrict__ Wo,
                         u16* __restrict__ xb, u16* __restrict__ Wcat, u16* __restrict__ Wob) {
  int i = (blockIdx.x * blockDim.x + threadIdx.x) * 4;
  const int stride = gridDim.x * blockDim.x * 4;
  for (; i < 8388608; i += stride) {
    const float* src;
    u16* dst;
    if (i < 4194304) {
      src = x + i; dst = xb + i;
    } else {
      const int j = i - 4194304;
      const int sel = j >> 20, off = j & 1048575;
      src = ((sel == 0) ? Wq : (sel == 1) ? Wk : (sel == 2) ? Wv : Wo) + off;
      dst = (sel < 3) ? (Wcat + j) : (Wob + off);
    }
    float4 v = *reinterpret_cast<const float4*>(src);
    u16x4 o = { f2bf(v.x), f2bf(v.y), f2bf(v.z), f2bf(v.w) };
    *reinterpret_cast<u16x4*>(dst) = o;
  }
}

#define QSCALE 0.18033688011112042f  /* 1/sqrt(64) * log2(e) */

// C = A @ B^T.  128x128 tile, BK=32, LDS double-buffer with counted vmcnt.
// LDS slot-swizzle retained (neutral at 2-phase, harmless).
// EPI 0: scatter Q(pre-scaled)/K/Vt.  EPI 1: fp32 out + bias.
template<int EPI>
__global__ __launch_bounds__(256) void gemm_bt(
    const u16* __restrict__ A, const u16* __restrict__ B,
    int M, int N, int K,
    u16* __restrict__ o0, u16* __restrict__ o1, u16* __restrict__ o2,
    float* __restrict__ fo, const float* __restrict__ bias)
{
  __shared__ __align__(16) u16 As[2][128 * 32];
  __shared__ __align__(16) u16 Bs[2][128 * 32];
  const int tid = threadIdx.x;
  const int w = tid >> 6, l = tid & 63;
  const int m0 = blockIdx.y * 128, n0 = blockIdx.x * 128;
  const int arow = (w << 4) + (l >> 2);
  const int aslot = (l & 3) ^ ((arow >> 1) & 3);   // pre-swizzled source slot
  const int acol = aslot << 3;
  const int wr = (w >> 1) << 6, wc = (w & 1) << 6;
  const int lr = l & 15, hi = l >> 4;
  f32x4 acc[4][4] = {};

  const u16* Ap = A + (size_t)(m0 + arow) * K + acol;
  const u16* Bp = B + (size_t)(n0 + arow) * K + acol;
  const int so = (w << 9);

  gload_lds16(Ap, &As[0][so]);
  gload_lds16(Ap + (size_t)64 * K, &As[0][so + 2048]);
  gload_lds16(Bp, &Bs[0][so]);
  gload_lds16(Bp + (size_t)64 * K, &Bs[0][so + 2048]);

  // fragment read byte offsets (swizzled to match the staged layout)
  int aoff[4], boff[4];
#pragma unroll
  for (int m = 0; m < 4; ++m) {
    const int row = wr + m * 16 + lr;
    aoff[m] = row * 64 + ((hi ^ ((row >> 1) & 3)) << 4);
  }
#pragma unroll
  for (int n = 0; n < 4; ++n) {
    const int row = wc + n * 16 + lr;
    boff[n] = row * 64 + ((hi ^ ((row >> 1) & 3)) << 4);
  }

  int buf = 0;
  for (int k0 = 0; k0 < K; k0 += 32) {
    if (k0 + 32 < K) {
      const int nb = buf ^ 1;
      gload_lds16(Ap + k0 + 32, &As[nb][so]);
      gload_lds16(Ap + (size_t)64 * K + k0 + 32, &As[nb][so + 2048]);
      gload_lds16(Bp + k0 + 32, &Bs[nb][so]);
      gload_lds16(Bp + (size_t)64 * K + k0 + 32, &Bs[nb][so + 2048]);
      asm volatile("s_waitcnt vmcnt(4)" ::: "memory");
    } else {
      asm volatile("s_waitcnt vmcnt(0)" ::: "memory");
    }
    __builtin_amdgcn_sched_barrier(0);
    __builtin_amdgcn_s_barrier();
    bf16x8 af[4], bfr[4];
#pragma unroll
    for (int m = 0; m < 4; ++m)
      af[m] = *(const bf16x8*)((const char*)&As[buf][0] + aoff[m]);
#pragma unroll
    for (int n = 0; n < 4; ++n)
      bfr[n] = *(const bf16x8*)((const char*)&Bs[buf][0] + boff[n]);
    __builtin_amdgcn_s_setprio(1);
#pragma unroll
    for (int m = 0; m < 4; ++m)
#pragma unroll
      for (int n = 0; n < 4; ++n)
        acc[m][n] = __builtin_amdgcn_mfma_f32_16x16x32_bf16(af[m], bfr[n], acc[m][n], 0, 0, 0);
    __builtin_amdgcn_s_setprio(0);
    __builtin_amdgcn_s_barrier();
    buf ^= 1;
  }

#pragma unroll
  for (int mm = 0; mm < 4; ++mm) {
#pragma unroll
    for (int nn = 0; nn < 4; ++nn) {
      const int ng = n0 + wc + nn * 16 + lr;
      if (EPI == 0) {
        const int mat = ng >> 10;
        const int col = ng & 1023;
        const int h = col >> 6, dh = col & 63;
#pragma unroll
        for (int r = 0; r < 4; ++r) {
          const int mg = m0 + wr + mm * 16 + (hi << 2) + r;
          const int b = mg >> 11, s = mg & 2047;
          if (mat == 0)
            o0[(((size_t)(b * 16 + h)) * 2048 + s) * 64 + dh] = f2bf(acc[mm][nn][r] * QSCALE);
          else if (mat == 1)
            o1[(((size_t)(b * 16 + h)) * 2048 + s) * 64 + dh] = f2bf(acc[mm][nn][r]);
          else
            o2[(((size_t)(b * 16 + h)) * 64 + dh) * 2048 + s] = f2bf(acc[mm][nn][r]);
        }
      } else {
        const float bv = bias[ng];
#pragma unroll
        for (int r = 0; r < 4; ++r) {
          const int mg = m0 + wr + mm * 16 + (hi << 2) + r;
          fo[(size_t)mg * N + ng] = acc[mm][nn][r] + bv;
        }
      }
    }
  }
}

// Flash attention, causal.  UNIFORM-WORK pairing + XCD clustering:
// 1-D grid 512; bid -> xcd=bid&7, j=bid>>3, bh=xcd+8*(j&3), p=j>>2.
// All 16 pair-blocks of a bh land on ONE XCD (4 bh x 512KB K/V = 2MB per
// 4MB XCD-L2); per-block work stays exactly uniform (33 phases), so the
// R14 occupancy confound is gone.  Inner pipeline: K/V reg-staged
// (global->reg, ds_write to buf^1 at phase end), ONE barrier per phase,
// loads issued 2 tiles ahead; swapped QK^T -> in-lane exp2 softmax;
// per-wave PT bounce.
__global__ __launch_bounds__(256) void flash_attn(
    const u16* __restrict__ Qg, const u16* __restrict__ Kg,
    const u16* __restrict__ Vtg, u16* __restrict__ ctx)
{
  __shared__ __align__(16) u16 Ks[2][4096];
  __shared__ __align__(16) u16 Vts[2][4096];
  __shared__ __align__(16) u16 PT[4][1024];
  const int tid = threadIdx.x, w = tid >> 6, l = tid & 63;
  const int lr = l & 15, hi = l >> 4;
  const int bid = blockIdx.x;
  const int xcd = bid & 7, j = bid >> 3;
  const int bh = xcd + ((j & 3) << 3);
  const int p = j >> 2;              // pair index [0,16)
  const size_t kqbase = (size_t)bh * (2048 * 64);
  const int h = bh & 15, b = bh >> 4;

  const int c0 = w * 128 + l;
  const int c1 = c0 + 64;
  const int r0 = c0 >> 3, p0 = c0 & 7;
  const int r1 = c1 >> 3, p1 = c1 & 7;
  const u16* kg0 = Kg + kqbase + r0 * 64 + p0 * 8;
  const u16* kg1 = Kg + kqbase + r1 * 64 + p1 * 8;
  const u16* vg0 = Vtg + kqbase + (size_t)r0 * 2048 + p0 * 8;
  const u16* vg1 = Vtg + kqbase + (size_t)r1 * 2048 + p1 * 8;
  const int kw0 = (r0 << 7) + ((p0 ^ (r0 & 7)) << 4);
  const int kw1 = (r1 << 7) + ((p1 ^ (r1 & 7)) << 4);

  for (int seg = 0; seg < 2; ++seg) {
    const int qt = seg ? (31 - p) : p;
    const int q0 = qt * 64;
    const int nkt = qt + 1;
    const int qg = q0 + w * 16 + lr;

    if (seg) __builtin_amdgcn_s_barrier();   // protect LDS reuse across segments

    bf16x8 qf[2];
    {
      const u16* qp = Qg + kqbase + (size_t)(q0 + w * 16 + lr) * 64 + hi * 8;
      qf[0] = *(const bf16x8*)(qp);
      qf[1] = *(const bf16x8*)(qp + 32);
    }

    f32x4 acc[4] = {};
    float lsum = 0.0f;

    // prologue: tile 0 -> regs -> buf0; issue tile 1 loads
    bf16x8 sk0 = *(const bf16x8*)kg0;
    bf16x8 sk1 = *(const bf16x8*)kg1;
    bf16x8 sv0 = *(const bf16x8*)vg0;
    bf16x8 sv1 = *(const bf16x8*)vg1;
    *(bf16x8*)((char*)&Ks[0][0] + kw0) = sk0;
    *(bf16x8*)((char*)&Ks[0][0] + kw1) = sk1;
    *(bf16x8*)((char*)&Vts[0][0] + kw0) = sv0;
    *(bf16x8*)((char*)&Vts[0][0] + kw1) = sv1;
    if (nkt > 1) {
      sk0 = *(const bf16x8*)(kg0 + 4096);
      sk1 = *(const bf16x8*)(kg1 + 4096);
      sv0 = *(const bf16x8*)(vg0 + 64);
      sv1 = *(const bf16x8*)(vg1 + 64);
    }
    asm volatile("s_waitcnt lgkmcnt(0)" ::: "memory");
    __builtin_amdgcn_sched_barrier(0);
    __builtin_amdgcn_s_barrier();

    int buf = 0;
    for (int kt = 0; kt < nkt; ++kt) {
      {
        const u16* ksb = &Ks[buf][0];
        const u16* vsb = &Vts[buf][0];
        f32x4 sv[4];
        __builtin_amdgcn_s_setprio(1);
#pragma unroll
        for (int cf = 0; cf < 4; ++cf) {
          f32x4 z = {};
#pragma unroll
          for (int ch = 0; ch < 2; ++ch) {
            const int krow = cf * 16 + lr;
            const int boff = ((krow << 7) + ((ch * 32 + hi * 8) << 1)) ^ ((krow & 7) << 4);
            bf16x8 kf = *(const bf16x8*)((const char*)ksb + boff);
            z = __builtin_amdgcn_mfma_f32_16x16x32_bf16(kf, qf[ch], z, 0, 0, 0);
          }
          sv[cf] = z;
        }
        __builtin_amdgcn_s_setprio(0);

        const bool diag = (kt == nkt - 1);
        const int kb = kt * 64 + hi * 4;
        float ts = 0.0f;
#pragma unroll
        for (int cf = 0; cf < 4; ++cf) {
          f32x4 pv;
#pragma unroll
          for (int r = 0; r < 4; ++r) {
            float s = sv[cf][r];
            if (diag && (kb + cf * 16 + r) > qg) s = -1e30f;
            pv[r] = exp2f(s);
          }
          sv[cf] = pv;
          ts += (pv[0] + pv[1]) + (pv[2] + pv[3]);
        }
        lsum += ts;

        {
          const int rowb = lr << 7;
          const int swz = (lr & 7) << 4;
#pragma unroll
          for (int cf = 0; cf < 4; ++cf) {
            uint32_t d0 = pk_bf16(sv[cf][0], sv[cf][1]);
            uint32_t d1 = pk_bf16(sv[cf][2], sv[cf][3]);
            uint2 val = { d0, d1 };
            const int boff = (rowb + ((cf * 16 + hi * 4) << 1)) ^ swz;
            *(uint2*)((char*)&PT[w][0] + boff) = val;
          }
        }

#pragma unroll
        for (int ch = 0; ch < 2; ++ch) {
          const int boffp = ((lr << 7) + (ch * 64 + hi * 16)) ^ ((lr & 7) << 4);
          bf16x8 pa = *(const bf16x8*)((const char*)&PT[w][0] + boffp);
          __builtin_amdgcn_s_setprio(1);
#pragma unroll
          for (int df = 0; df < 4; ++df) {
            const int vrow = df * 16 + lr;
            const int boffv = ((vrow << 7) + ((ch * 32 + hi * 8) << 1)) ^ ((vrow & 7) << 4);
            bf16x8 vf = *(const bf16x8*)((const char*)vsb + boffv);
            acc[df] = __builtin_amdgcn_mfma_f32_16x16x32_bf16(pa, vf, acc[df], 0, 0, 0);
          }
          __builtin_amdgcn_s_setprio(0);
        }
      }
      if (kt + 1 < nkt) {
        char* kb_ = (char*)&Ks[buf ^ 1][0];
        char* vb_ = (char*)&Vts[buf ^ 1][0];
        *(bf16x8*)(kb_ + kw0) = sk0;
        *(bf16x8*)(kb_ + kw1) = sk1;
        *(bf16x8*)(vb_ + kw0) = sv0;
        *(bf16x8*)(vb_ + kw1) = sv1;
        if (kt + 2 < nkt) {
          sk0 = *(const bf16x8*)(kg0 + (size_t)(kt + 2) * 4096);
          sk1 = *(const bf16x8*)(kg1 + (size_t)(kt + 2) * 4096);
          sv0 = *(const bf16x8*)(vg0 + (kt + 2) * 64);
          sv1 = *(const bf16x8*)(vg1 + (kt + 2) * 64);
        }
        asm volatile("s_waitcnt lgkmcnt(0)" ::: "memory");
        __builtin_amdgcn_sched_barrier(0);
        __builtin_amdgcn_s_barrier();
      }
      buf ^= 1;
    }

    float lf = lsum;
    lf += __shfl_xor(lf, 16);
    lf += __shfl_xor(lf, 32);
#pragma unroll
    for (int r = 0; r < 4; ++r) {
      const float inv = 1.0f / __shfl(lf, hi * 4 + r);
      const int s = q0 + w * 16 + hi * 4 + r;
      const size_t rowbase = ((size_t)(b * 2048 + s)) * 1024 + h * 64;
#pragma unroll
      for (int df = 0; df < 4; ++df)
        ctx[rowbase + df * 16 + lr] = f2bf(acc[df][r] * inv);
    }
  }
}

extern "C" void kernel_launch(void* const* d_in, const int* in_sizes, int n_in,
                              void* d_out, int out_size, void* d_ws, size_t ws_size,
                              hipStream_t stream) {
  const float* x  = (const float*)d_in[0];
  const float* Wq = (const float*)d_in[1];
  const float* Wk = (const float*)d_in[2];
  const float* Wv = (const float*)d_in[3];
  const float* Wo = (const float*)d_in[4];
  const float* bo = (const float*)d_in[5];
  float* out = (float*)d_out;

  const size_t MB = 1ull << 20;
  if (ws_size < 48 * MB) return;  // loud failure instead of corruption
  char* ws = (char*)d_ws;
  u16* xb   = (u16*)(ws);             // [4096][1024]
  u16* Wcat = (u16*)(ws + 8 * MB);    // [3072][1024]  (Wq|Wk|Wv)
  u16* Wob  = (u16*)(ws + 14 * MB);   // [1024][1024]
  u16* Qb   = (u16*)(ws + 16 * MB);   // [B,H,S,DH]  (pre-scaled)
  u16* Kb   = (u16*)(ws + 24 * MB);   // [B,H,S,DH]
  u16* Vtb  = (u16*)(ws + 32 * MB);   // [B,H,DH,S]
  u16* ctxb = (u16*)(ws + 40 * MB);   // [4096][1024]

  hipLaunchKernelGGL(cast_all, dim3(4096), dim3(256), 0, stream,
                     x, Wq, Wk, Wv, Wo, xb, Wcat, Wob);
  hipLaunchKernelGGL((gemm_bt<0>), dim3(24, 32), dim3(256), 0, stream,
                     xb, Wcat, 4096, 3072, 1024, Qb, Kb, Vtb, (float*)nullptr, (const float*)nullptr);
  hipLaunchKernelGGL(flash_attn, dim3(512), dim3(256), 0, stream, Qb, Kb, Vtb, ctxb);
  hipLaunchKernelGGL((gemm_bt<1>), dim3(8, 32), dim3(256), 0, stream,
                     ctxb, Wob, 4096, 1024, 1024,
                     (u16*)nullptr, (u16*)nullptr, (u16*)nullptr, out, bo);
}

// Round 24
// 120.225 us; speedup vs baseline: 1.1456x; 1.0103x over previous
//
#include <hip/hip_runtime.h>
#include <stdint.h>

typedef unsigned short u16;
typedef __attribute__((ext_vector_type(8))) short bf16x8;
typedef __attribute__((ext_vector_type(4))) float f32x4;
typedef __attribute__((ext_vector_type(4))) unsigned short u16x4;

__device__ __forceinline__ u16 f2bf(float f) {
  union { float f; uint32_t u; } c; c.f = f;
  uint32_t u = c.u;
  return (u16)((u + 0x7fffu + ((u >> 16) & 1u)) >> 16);
}

__device__ __forceinline__ uint32_t pk_bf16(float lo, float hi) {
  uint32_t d;
  asm("v_cvt_pk_bf16_f32 %0, %1, %2" : "=v"(d) : "v"(lo), "v"(hi));
  return d;
}

__device__ __forceinline__ void gload_lds16(const u16* g, u16* l) {
  __builtin_amdgcn_global_load_lds(
      (const __attribute__((address_space(1))) void*)g,
      (__attribute__((address_space(3))) void*)l, 16, 0, 0);
}

// one launch: x -> xb, Wq|Wk|Wv -> Wcat, Wo -> Wob
__global__ void cast_all(const float* __restrict__ x,
                         const float* __restrict__ Wq, const float* __restrict__ Wk,
                         const float* __restrict__ Wv, const float* __restrict__ Wo,
                         u16* __restrict__ xb, u16* __restrict__ Wcat, u16* __restrict__ Wob) {
  int i = (blockIdx.x * blockDim.x + threadIdx.x) * 4;
  const int stride = gridDim.x * blockDim.x * 4;
  for (; i < 8388608; i += stride) {
    const float* src;
    u16* dst;
    if (i < 4194304) {
      src = x + i; dst = xb + i;
    } else {
      const int j = i - 4194304;
      const int sel = j >> 20, off = j & 1048575;
      src = ((sel == 0) ? Wq : (sel == 1) ? Wk : (sel == 2) ? Wv : Wo) + off;
      dst = (sel < 3) ? (Wcat + j) : (Wob + off);
    }
    float4 v = *reinterpret_cast<const float4*>(src);
    u16x4 o = { f2bf(v.x), f2bf(v.y), f2bf(v.z), f2bf(v.w) };
    *reinterpret_cast<u16x4*>(dst) = o;
  }
}

#define QSCALE 0.18033688011112042f  /* 1/sqrt(64) * log2(e) */

// C = A @ B^T.  128x128 tile, BK=32, LDS double-buffer with counted vmcnt.
// EPI 0: scatter Q(pre-scaled)/K/Vt.  EPI 1: fp32 out + bias.
template<int EPI>
__global__ __launch_bounds__(256) void gemm_bt(
    const u16* __restrict__ A, const u16* __restrict__ B,
    int M, int N, int K,
    u16* __restrict__ o0, u16* __restrict__ o1, u16* __restrict__ o2,
    float* __restrict__ fo, const float* __restrict__ bias)
{
  __shared__ __align__(16) u16 As[2][128 * 32];
  __shared__ __align__(16) u16 Bs[2][128 * 32];
  const int tid = threadIdx.x;
  const int w = tid >> 6, l = tid & 63;
  const int m0 = blockIdx.y * 128, n0 = blockIdx.x * 128;
  const int arow = (w << 4) + (l >> 2);
  const int aslot = (l & 3) ^ ((arow >> 1) & 3);   // pre-swizzled source slot
  const int acol = aslot << 3;
  const int wr = (w >> 1) << 6, wc = (w & 1) << 6;
  const int lr = l & 15, hi = l >> 4;
  f32x4 acc[4][4] = {};

  const u16* Ap = A + (size_t)(m0 + arow) * K + acol;
  const u16* Bp = B + (size_t)(n0 + arow) * K + acol;
  const int so = (w << 9);

  gload_lds16(Ap, &As[0][so]);
  gload_lds16(Ap + (size_t)64 * K, &As[0][so + 2048]);
  gload_lds16(Bp, &Bs[0][so]);
  gload_lds16(Bp + (size_t)64 * K, &Bs[0][so + 2048]);

  // fragment read byte offsets (swizzled to match the staged layout)
  int aoff[4], boff[4];
#pragma unroll
  for (int m = 0; m < 4; ++m) {
    const int row = wr + m * 16 + lr;
    aoff[m] = row * 64 + ((hi ^ ((row >> 1) & 3)) << 4);
  }
#pragma unroll
  for (int n = 0; n < 4; ++n) {
    const int row = wc + n * 16 + lr;
    boff[n] = row * 64 + ((hi ^ ((row >> 1) & 3)) << 4);
  }

  int buf = 0;
  for (int k0 = 0; k0 < K; k0 += 32) {
    if (k0 + 32 < K) {
      const int nb = buf ^ 1;
      gload_lds16(Ap + k0 + 32, &As[nb][so]);
      gload_lds16(Ap + (size_t)64 * K + k0 + 32, &As[nb][so + 2048]);
      gload_lds16(Bp + k0 + 32, &Bs[nb][so]);
      gload_lds16(Bp + (size_t)64 * K + k0 + 32, &Bs[nb][so + 2048]);
      asm volatile("s_waitcnt vmcnt(4)" ::: "memory");
    } else {
      asm volatile("s_waitcnt vmcnt(0)" ::: "memory");
    }
    __builtin_amdgcn_sched_barrier(0);
    __builtin_amdgcn_s_barrier();
    bf16x8 af[4], bfr[4];
#pragma unroll
    for (int m = 0; m < 4; ++m)
      af[m] = *(const bf16x8*)((const char*)&As[buf][0] + aoff[m]);
#pragma unroll
    for (int n = 0; n < 4; ++n)
      bfr[n] = *(const bf16x8*)((const char*)&Bs[buf][0] + boff[n]);
    __builtin_amdgcn_s_setprio(1);
#pragma unroll
    for (int m = 0; m < 4; ++m)
#pragma unroll
      for (int n = 0; n < 4; ++n)
        acc[m][n] = __builtin_amdgcn_mfma_f32_16x16x32_bf16(af[m], bfr[n], acc[m][n], 0, 0, 0);
    __builtin_amdgcn_s_setprio(0);
    __builtin_amdgcn_s_barrier();
    buf ^= 1;
  }

#pragma unroll
  for (int mm = 0; mm < 4; ++mm) {
#pragma unroll
    for (int nn = 0; nn < 4; ++nn) {
      const int ng = n0 + wc + nn * 16 + lr;
      if (EPI == 0) {
        const int mat = ng >> 10;
        const int col = ng & 1023;
        const int h = col >> 6, dh = col & 63;
#pragma unroll
        for (int r = 0; r < 4; ++r) {
          const int mg = m0 + wr + mm * 16 + (hi << 2) + r;
          const int b = mg >> 11, s = mg & 2047;
          if (mat == 0)
            o0[(((size_t)(b * 16 + h)) * 2048 + s) * 64 + dh] = f2bf(acc[mm][nn][r] * QSCALE);
          else if (mat == 1)
            o1[(((size_t)(b * 16 + h)) * 2048 + s) * 64 + dh] = f2bf(acc[mm][nn][r]);
          else
            o2[(((size_t)(b * 16 + h)) * 64 + dh) * 2048 + s] = f2bf(acc[mm][nn][r]);
        }
      } else {
        const float bv = bias[ng];
#pragma unroll
        for (int r = 0; r < 4; ++r) {
          const int mg = m0 + wr + mm * 16 + (hi << 2) + r;
          fo[(size_t)mg * N + ng] = acc[mm][nn][r] + bv;
        }
      }
    }
  }
}

// Flash attention, causal.  UNIFORM-WORK pairing + XCD clustering (R22).
// Row-sums on the MFMA pipe — acc_ls = mfma(pa, ones, acc_ls) per k-chunk
// replaces 16 VALU adds/phase; every lane's acc_ls[r] ends as the COMPLETE
// row sum for q-row hi*4+r (all D-columns identical), so the epilogue
// normalizer is lane-local (no shuffles).  Denominator uses the
// bf16-rounded P values — consistent with the PV numerator.
__global__ __launch_bounds__(256) void flash_attn(
    const u16* __restrict__ Qg, const u16* __restrict__ Kg,
    const u16* __restrict__ Vtg, u16* __restrict__ ctx)
{
  __shared__ __align__(16) u16 Ks[2][4096];
  __shared__ __align__(16) u16 Vts[2][4096];
  __shared__ __align__(16) u16 PT[4][1024];
  const int tid = threadIdx.x, w = tid >> 6, l = tid & 63;
  const int lr = l & 15, hi = l >> 4;
  const int bid = blockIdx.x;
  const int xcd = bid & 7, j = bid >> 3;
  const int bh = xcd + ((j & 3) << 3);
  const int p = j >> 2;              // pair index [0,16)
  const size_t kqbase = (size_t)bh * (2048 * 64);
  const int h = bh & 15, b = bh >> 4;

  // ones B-fragment (bf16 1.0 = 0x3F80)
  bf16x8 onesf;
#pragma unroll
  for (int i = 0; i < 8; ++i) onesf[i] = (short)0x3F80;

  const int c0 = w * 128 + l;
  const int c1 = c0 + 64;
  const int r0 = c0 >> 3, p0 = c0 & 7;
  const int r1 = c1 >> 3, p1 = c1 & 7;
  const u16* kg0 = Kg + kqbase + r0 * 64 + p0 * 8;
  const u16* kg1 = Kg + kqbase + r1 * 64 + p1 * 8;
  const u16* vg0 = Vtg + kqbase + (size_t)r0 * 2048 + p0 * 8;
  const u16* vg1 = Vtg + kqbase + (size_t)r1 * 2048 + p1 * 8;
  const int kw0 = (r0 << 7) + ((p0 ^ (r0 & 7)) << 4);
  const int kw1 = (r1 << 7) + ((p1 ^ (r1 & 7)) << 4);

  for (int seg = 0; seg < 2; ++seg) {
    const int qt = seg ? (31 - p) : p;
    const int q0 = qt * 64;
    const int nkt = qt + 1;
    const int qg = q0 + w * 16 + lr;

    if (seg) __builtin_amdgcn_s_barrier();   // protect LDS reuse across segments

    bf16x8 qf[2];
    {
      const u16* qp = Qg + kqbase + (size_t)(q0 + w * 16 + lr) * 64 + hi * 8;
      qf[0] = *(const bf16x8*)(qp);
      qf[1] = *(const bf16x8*)(qp + 32);
    }

    f32x4 acc[4] = {};
    f32x4 acc_ls = {};

    // prologue: tile 0 -> regs -> buf0; issue tile 1 loads
    bf16x8 sk0 = *(const bf16x8*)kg0;
    bf16x8 sk1 = *(const bf16x8*)kg1;
    bf16x8 sv0 = *(const bf16x8*)vg0;
    bf16x8 sv1 = *(const bf16x8*)vg1;
    *(bf16x8*)((char*)&Ks[0][0] + kw0) = sk0;
    *(bf16x8*)((char*)&Ks[0][0] + kw1) = sk1;
    *(bf16x8*)((char*)&Vts[0][0] + kw0) = sv0;
    *(bf16x8*)((char*)&Vts[0][0] + kw1) = sv1;
    if (nkt > 1) {
      sk0 = *(const bf16x8*)(kg0 + 4096);
      sk1 = *(const bf16x8*)(kg1 + 4096);
      sv0 = *(const bf16x8*)(vg0 + 64);
      sv1 = *(const bf16x8*)(vg1 + 64);
    }
    asm volatile("s_waitcnt lgkmcnt(0)" ::: "memory");
    __builtin_amdgcn_sched_barrier(0);
    __builtin_amdgcn_s_barrier();

    int buf = 0;
    for (int kt = 0; kt < nkt; ++kt) {
      {
        const u16* ksb = &Ks[buf][0];
        const u16* vsb = &Vts[buf][0];
        f32x4 sv[4];
        __builtin_amdgcn_s_setprio(1);
#pragma unroll
        for (int cf = 0; cf < 4; ++cf) {
          f32x4 z = {};
#pragma unroll
          for (int ch = 0; ch < 2; ++ch) {
            const int krow = cf * 16 + lr;
            const int boff = ((krow << 7) + ((ch * 32 + hi * 8) << 1)) ^ ((krow & 7) << 4);
            bf16x8 kf = *(const bf16x8*)((const char*)ksb + boff);
            z = __builtin_amdgcn_mfma_f32_16x16x32_bf16(kf, qf[ch], z, 0, 0, 0);
          }
          sv[cf] = z;
        }
        __builtin_amdgcn_s_setprio(0);

        const bool diag = (kt == nkt - 1);
        const int kb = kt * 64 + hi * 4;
#pragma unroll
        for (int cf = 0; cf < 4; ++cf) {
          f32x4 pv;
#pragma unroll
          for (int r = 0; r < 4; ++r) {
            float s = sv[cf][r];
            if (diag && (kb + cf * 16 + r) > qg) s = -1e30f;
            pv[r] = exp2f(s);
          }
          sv[cf] = pv;
        }

        {
          const int rowb = lr << 7;
          const int swz = (lr & 7) << 4;
#pragma unroll
          for (int cf = 0; cf < 4; ++cf) {
            uint32_t d0 = pk_bf16(sv[cf][0], sv[cf][1]);
            uint32_t d1 = pk_bf16(sv[cf][2], sv[cf][3]);
            uint2 val = { d0, d1 };
            const int boff = (rowb + ((cf * 16 + hi * 4) << 1)) ^ swz;
            *(uint2*)((char*)&PT[w][0] + boff) = val;
          }
        }

#pragma unroll
        for (int ch = 0; ch < 2; ++ch) {
          const int boffp = ((lr << 7) + (ch * 64 + hi * 16)) ^ ((lr & 7) << 4);
          bf16x8 pa = *(const bf16x8*)((const char*)&PT[w][0] + boffp);
          __builtin_amdgcn_s_setprio(1);
          acc_ls = __builtin_amdgcn_mfma_f32_16x16x32_bf16(pa, onesf, acc_ls, 0, 0, 0);
#pragma unroll
          for (int df = 0; df < 4; ++df) {
            const int vrow = df * 16 + lr;
            const int boffv = ((vrow << 7) + ((ch * 32 + hi * 8) << 1)) ^ ((vrow & 7) << 4);
            bf16x8 vf = *(const bf16x8*)((const char*)vsb + boffv);
            acc[df] = __builtin_amdgcn_mfma_f32_16x16x32_bf16(pa, vf, acc[df], 0, 0, 0);
          }
          __builtin_amdgcn_s_setprio(0);
        }
      }
      if (kt + 1 < nkt) {
        char* kb_ = (char*)&Ks[buf ^ 1][0];
        char* vb_ = (char*)&Vts[buf ^ 1][0];
        *(bf16x8*)(kb_ + kw0) = sk0;
        *(bf16x8*)(kb_ + kw1) = sk1;
        *(bf16x8*)(vb_ + kw0) = sv0;
        *(bf16x8*)(vb_ + kw1) = sv1;
        if (kt + 2 < nkt) {
          sk0 = *(const bf16x8*)(kg0 + (size_t)(kt + 2) * 4096);
          sk1 = *(const bf16x8*)(kg1 + (size_t)(kt + 2) * 4096);
          sv0 = *(const bf16x8*)(vg0 + (kt + 2) * 64);
          sv1 = *(const bf16x8*)(vg1 + (kt + 2) * 64);
        }
        asm volatile("s_waitcnt lgkmcnt(0)" ::: "memory");
        __builtin_amdgcn_sched_barrier(0);
        __builtin_amdgcn_s_barrier();
      }
      buf ^= 1;
    }

    // epilogue: acc_ls[r] is the full row sum for q-row hi*4+r (lane-local)
#pragma unroll
    for (int r = 0; r < 4; ++r) {
      const float inv = 1.0f / acc_ls[r];
      const int s = q0 + w * 16 + hi * 4 + r;
      const size_t rowbase = ((size_t)(b * 2048 + s)) * 1024 + h * 64;
#pragma unroll
      for (int df = 0; df < 4; ++df)
        ctx[rowbase + df * 16 + lr] = f2bf(acc[df][r] * inv);
    }
  }
}

extern "C" void kernel_launch(void* const* d_in, const int* in_sizes, int n_in,
                              void* d_out, int out_size, void* d_ws, size_t ws_size,
                              hipStream_t stream) {
  const float* x  = (const float*)d_in[0];
  const float* Wq = (const float*)d_in[1];
  const float* Wk = (const float*)d_in[2];
  const float* Wv = (const float*)d_in[3];
  const float* Wo = (const float*)d_in[4];
  const float* bo = (const float*)d_in[5];
  float* out = (float*)d_out;

  const size_t MB = 1ull << 20;
  if (ws_size < 48 * MB) return;  // loud failure instead of corruption
  char* ws = (char*)d_ws;
  u16* xb   = (u16*)(ws);             // [4096][1024]
  u16* Wcat = (u16*)(ws + 8 * MB);    // [3072][1024]  (Wq|Wk|Wv)
  u16* Wob  = (u16*)(ws + 14 * MB);   // [1024][1024]
  u16* Qb   = (u16*)(ws + 16 * MB);   // [B,H,S,DH]  (pre-scaled)
  u16* Kb   = (u16*)(ws + 24 * MB);   // [B,H,S,DH]
  u16* Vtb  = (u16*)(ws + 32 * MB);   // [B,H,DH,S]
  u16* ctxb = (u16*)(ws + 40 * MB);   // [4096][1024]

  hipLaunchKernelGGL(cast_all, dim3(4096), dim3(256), 0, stream,
                     x, Wq, Wk, Wv, Wo, xb, Wcat, Wob);
  hipLaunchKernelGGL((gemm_bt<0>), dim3(24, 32), dim3(256), 0, stream,
                     xb, Wcat, 4096, 3072, 1024, Qb, Kb, Vtb, (float*)nullptr, (const float*)nullptr);
  hipLaunchKernelGGL(flash_attn, dim3(512), dim3(256), 0, stream, Qb, Kb, Vtb, ctxb);
  hipLaunchKernelGGL((gemm_bt<1>), dim3(8, 32), dim3(256), 0, stream,
                     ctxb, Wob, 4096, 1024, 1024,
                     (u16*)nullptr, (u16*)nullptr, (u16*)nullptr, out, bo);
}